// Round 4
// baseline (214.407 us; speedup 1.0000x reference)
//
#include <hip/hip_runtime.h>
#include <math.h>

#define IN_NODES  4096
#define OUT_NODES 1024
#define ROW_ELEMS 16384                // floats per in-node slice (1024*16)
#define ROW_C4    4096                 // float4 chunks per in-node slice

typedef unsigned short u16;
typedef unsigned int   u32;

__device__ __forceinline__ float dot4(const float4 a, const float4 b) {
    return a.x*b.x + a.y*b.y + a.z*b.z + a.w*b.w;
}
__device__ __forceinline__ void fma4(float4& a, const float c, const float4 u) {
    a.x += c*u.x; a.y += c*u.y; a.z += c*u.z; a.w += c*u.w;
}
__device__ __forceinline__ void add4(float4& a, const float4 u) {
    a.x += u.x; a.y += u.y; a.z += u.z; a.w += u.w;
}
__device__ __forceinline__ float b2f1(u16 u) {
    return __uint_as_float(((u32)u) << 16);
}
__device__ __forceinline__ float4 b2f(ushort4 u) {
    return make_float4(b2f1(u.x), b2f1(u.y), b2f1(u.z), b2f1(u.w));
}
__device__ __forceinline__ u16 f2b(float x) {            // RNE f32->bf16
    u32 b = __float_as_uint(x);
    return (u16)((b + 0x7FFFu + ((b >> 16) & 1u)) >> 16);
}
__device__ __forceinline__ ushort4 f2b4(float4 v) {
    ushort4 r; r.x = f2b(v.x); r.y = f2b(v.y); r.z = f2b(v.z); r.w = f2b(v.w);
    return r;
}

// ---------------------------------------------------------------------------
// Pass 1 (uniform c = 1/1024): streaming reduce of uh; optionally emits a
// bf16 copy for later passes. 512 threads: thread (wave,lane) owns chunks
// c4 = wave*512 + j*64 + lane, j=0..7 -> every load is a contiguous 1KB
// wave access. ~80 VGPR, no barriers.
// ---------------------------------------------------------------------------
template <bool WBF16>
__global__ __launch_bounds__(512, 4) void pass_uniform(const float* __restrict__ uh,
                                                       float* __restrict__ part,
                                                       u16* __restrict__ uh2,
                                                       int per_block) {
    const int t  = threadIdx.x;
    const int c0 = ((t >> 6) << 9) + (t & 63);

    float4 acc[8];
    #pragma unroll
    for (int j = 0; j < 8; ++j) acc[j] = make_float4(0.f, 0.f, 0.f, 0.f);

    const size_t i0 = (size_t)blockIdx.x * per_block;
    const float4* p = reinterpret_cast<const float4*>(uh) + i0 * ROW_C4 + c0;
    ushort4*      q = WBF16 ? reinterpret_cast<ushort4*>(uh2) + i0 * ROW_C4 + c0
                            : nullptr;

    for (int g = 0; g < per_block; ++g) {
        float4 u[8];
        #pragma unroll
        for (int j = 0; j < 8; ++j) u[j] = p[j * 64];
        #pragma unroll
        for (int j = 0; j < 8; ++j) add4(acc[j], u[j]);
        if (WBF16) {
            #pragma unroll
            for (int j = 0; j < 8; ++j) q[j * 64] = f2b4(u[j]);
            q += ROW_C4;
        }
        p += ROW_C4;
    }

    const float c = 1.0f / OUT_NODES;
    float4* sp = reinterpret_cast<float4*>(part) + (size_t)blockIdx.x * ROW_C4 + c0;
    #pragma unroll
    for (int j = 0; j < 8; ++j) {
        acc[j].x *= c; acc[j].y *= c; acc[j].z *= c; acc[j].w *= c;
        sp[j * 64] = acc[j];
    }
}

// ---------------------------------------------------------------------------
// Softmax pass, bf16 input. Out-node o = c4>>2 lives in a 4-lane quad ->
// quad shfl reduce gives d[o]; block sum of exp via wave shfl + 8-slot LDS.
// Distance-1 in-node prefetch; V and acc in registers. ~120 VGPR at
// launch_bounds(512,4) -> 2 blocks/CU so barriers overlap across blocks.
// No max-subtraction: |d| <= ||V||*4sigma < ~10, f32 exp is safe.
// ---------------------------------------------------------------------------
__global__ __launch_bounds__(512, 4) void pass_soft_bf16(const u16* __restrict__ uh2,
                                                         const float* __restrict__ V,
                                                         float* __restrict__ part,
                                                         int per_block) {
    const int t    = threadIdx.x;
    const int wave = t >> 6;
    const int lane = t & 63;
    const int c0   = (wave << 9) + lane;

    __shared__ float red8[8];
    __shared__ float redS;

    float4 v[8];
    {
        const float4* vp = reinterpret_cast<const float4*>(V) + c0;
        #pragma unroll
        for (int j = 0; j < 8; ++j) v[j] = vp[j * 64];
    }

    float4 acc[8];
    #pragma unroll
    for (int j = 0; j < 8; ++j) acc[j] = make_float4(0.f, 0.f, 0.f, 0.f);

    const ushort4* p = reinterpret_cast<const ushort4*>(uh2)
                     + (size_t)blockIdx.x * per_block * ROW_C4 + c0;
    ushort4 cur[8];
    #pragma unroll
    for (int j = 0; j < 8; ++j) cur[j] = p[j * 64];

    for (int g = 0; g < per_block; ++g) {
        ushort4 nxt[8];
        const ushort4* pn = p + ROW_C4;
        if (g + 1 < per_block) {
            #pragma unroll
            for (int j = 0; j < 8; ++j) nxt[j] = pn[j * 64];
        }

        float d[8];
        #pragma unroll
        for (int j = 0; j < 8; ++j) d[j] = dot4(b2f(cur[j]), v[j]);
        #pragma unroll
        for (int j = 0; j < 8; ++j) {
            d[j] += __shfl_xor(d[j], 1);
            d[j] += __shfl_xor(d[j], 2);
        }

        float e[8];
        float etot = 0.f;
        #pragma unroll
        for (int j = 0; j < 8; ++j) { e[j] = __expf(d[j]); etot += e[j]; }

        #pragma unroll
        for (int off = 32; off; off >>= 1) etot += __shfl_xor(etot, off);
        if (lane == 0) red8[wave] = etot;
        __syncthreads();
        if (wave == 0) {
            float s = (lane < 8) ? red8[lane] : 0.f;
            s += __shfl_xor(s, 4); s += __shfl_xor(s, 2); s += __shfl_xor(s, 1);
            if (lane == 0) redS = s;
        }
        __syncthreads();
        const float inv = 4.0f / redS;   // each out-node counted 4x (quad)

        #pragma unroll
        for (int j = 0; j < 8; ++j) fma4(acc[j], e[j] * inv, b2f(cur[j]));

        #pragma unroll
        for (int j = 0; j < 8; ++j) cur[j] = nxt[j];
        p = pn;
    }

    float4* sp = reinterpret_cast<float4*>(part) + (size_t)blockIdx.x * ROW_C4 + c0;
    #pragma unroll
    for (int j = 0; j < 8; ++j) sp[j * 64] = acc[j];
}

// ---------------------------------------------------------------------------
// Softmax pass, f32 input (fallback when workspace can't hold the bf16 copy).
// Same structure, no prefetch (register budget).
// ---------------------------------------------------------------------------
__global__ __launch_bounds__(512, 4) void pass_soft_f32(const float* __restrict__ uh,
                                                        const float* __restrict__ V,
                                                        float* __restrict__ part,
                                                        int per_block) {
    const int t    = threadIdx.x;
    const int wave = t >> 6;
    const int lane = t & 63;
    const int c0   = (wave << 9) + lane;

    __shared__ float red8[8];
    __shared__ float redS;

    float4 v[8];
    {
        const float4* vp = reinterpret_cast<const float4*>(V) + c0;
        #pragma unroll
        for (int j = 0; j < 8; ++j) v[j] = vp[j * 64];
    }

    float4 acc[8];
    #pragma unroll
    for (int j = 0; j < 8; ++j) acc[j] = make_float4(0.f, 0.f, 0.f, 0.f);

    const float4* p = reinterpret_cast<const float4*>(uh)
                    + (size_t)blockIdx.x * per_block * ROW_C4 + c0;

    for (int g = 0; g < per_block; ++g) {
        float4 u[8];
        #pragma unroll
        for (int j = 0; j < 8; ++j) u[j] = p[j * 64];

        float d[8];
        #pragma unroll
        for (int j = 0; j < 8; ++j) d[j] = dot4(u[j], v[j]);
        #pragma unroll
        for (int j = 0; j < 8; ++j) {
            d[j] += __shfl_xor(d[j], 1);
            d[j] += __shfl_xor(d[j], 2);
        }

        float e[8];
        float etot = 0.f;
        #pragma unroll
        for (int j = 0; j < 8; ++j) { e[j] = __expf(d[j]); etot += e[j]; }

        #pragma unroll
        for (int off = 32; off; off >>= 1) etot += __shfl_xor(etot, off);
        if (lane == 0) red8[wave] = etot;
        __syncthreads();
        if (wave == 0) {
            float s = (lane < 8) ? red8[lane] : 0.f;
            s += __shfl_xor(s, 4); s += __shfl_xor(s, 2); s += __shfl_xor(s, 1);
            if (lane == 0) redS = s;
        }
        __syncthreads();
        const float inv = 4.0f / redS;

        #pragma unroll
        for (int j = 0; j < 8; ++j) fma4(acc[j], e[j] * inv, u[j]);

        p += ROW_C4;
    }

    float4* sp = reinterpret_cast<float4*>(part) + (size_t)blockIdx.x * ROW_C4 + c0;
    #pragma unroll
    for (int j = 0; j < 8; ++j) sp[j * 64] = acc[j];
}

// ---------------------------------------------------------------------------
// Reduce partials -> s, squash -> v, out, cumulative V.
// 256 blocks x 256 thr: 4 threads per output (q = t&3 splits the G partials),
// 8-stream unroll for memory ILP. Quad shfl combines the 4 partial sums;
// a wave covers exactly one out-node's 16 f-elements -> xor{4,8,16,32}
// butterfly yields sum of squares (one representative per quad per class).
// ---------------------------------------------------------------------------
__global__ __launch_bounds__(256) void reduce_squash(const float* __restrict__ part,
                                                     float* __restrict__ V,
                                                     float* __restrict__ out,
                                                     int G, int first) {
    const int t    = threadIdx.x;
    const int gidx = blockIdx.x * 64 + (t >> 2);   // o*16 + f
    const int q    = t & 3;

    const float* p = part + gidx;
    float a0=0.f,a1=0.f,a2=0.f,a3=0.f,a4=0.f,a5=0.f,a6=0.f,a7=0.f;
    int b = q;
    for (; b + 28 < G; b += 32) {
        a0 += p[(size_t)(b     ) * ROW_ELEMS];
        a1 += p[(size_t)(b +  4) * ROW_ELEMS];
        a2 += p[(size_t)(b +  8) * ROW_ELEMS];
        a3 += p[(size_t)(b + 12) * ROW_ELEMS];
        a4 += p[(size_t)(b + 16) * ROW_ELEMS];
        a5 += p[(size_t)(b + 20) * ROW_ELEMS];
        a6 += p[(size_t)(b + 24) * ROW_ELEMS];
        a7 += p[(size_t)(b + 28) * ROW_ELEMS];
    }
    for (; b < G; b += 4) a0 += p[(size_t)b * ROW_ELEMS];
    float s = ((a0 + a1) + (a2 + a3)) + ((a4 + a5) + (a6 + a7));

    s += __shfl_xor(s, 1);      // combine the 4 q-partials (quad shares gidx)
    s += __shfl_xor(s, 2);

    float sq = s * s;           // wave = one out-node; sum over 16 f's
    sq += __shfl_xor(sq, 4);
    sq += __shfl_xor(sq, 8);
    sq += __shfl_xor(sq, 16);
    sq += __shfl_xor(sq, 32);

    const float scale = sq / ((1.0f + sq) * sqrtf(sq));
    const float v = s * scale;

    out[gidx] = v;                                  // 4 lanes write same value
    V[gidx]   = first ? v : (V[gidx] + v);
}

// ---------------------------------------------------------------------------
extern "C" void kernel_launch(void* const* d_in, const int* in_sizes, int n_in,
                              void* d_out, int out_size, void* d_ws, size_t ws_size,
                              hipStream_t stream) {
    const float* uh  = (const float*)d_in[0];
    float*       out = (float*)d_out;

    char*  ws   = (char*)d_ws;
    float* V    = (float*)ws;                      // 64 KB
    float* part = (float*)(ws + 65536);            // G * 64 KB

    int G = 512;
    while (G > 4 && ws_size < 65536ull * (size_t)(G + 1)) G >>= 1;
    const int per_block = IN_NODES / G;

    const size_t needA = 65536ull * 513ull + (size_t)IN_NODES * ROW_ELEMS * 2ull;
    const bool useA = (G == 512) && (ws_size >= needA);

    if (useA) {
        u16* uh2 = (u16*)(ws + 65536ull * 513ull); // 128 MB bf16 copy
        pass_uniform<true><<<512, 512, 0, stream>>>(uh, part, uh2, 8);
        reduce_squash<<<256, 256, 0, stream>>>(part, V, out, 512, 1);
        for (int it = 1; it < 3; ++it) {
            pass_soft_bf16<<<512, 512, 0, stream>>>(uh2, V, part, 8);
            reduce_squash<<<256, 256, 0, stream>>>(part, V, out, 512, 0);
        }
    } else {
        pass_uniform<false><<<G, 512, 0, stream>>>(uh, part, nullptr, per_block);
        reduce_squash<<<256, 256, 0, stream>>>(part, V, out, G, 1);
        for (int it = 1; it < 3; ++it) {
            pass_soft_f32<<<G, 512, 0, stream>>>(uh, V, part, per_block);
            reduce_squash<<<256, 256, 0, stream>>>(part, V, out, G, 0);
        }
    }
}